// Round 7
// baseline (307.479 us; speedup 1.0000x reference)
//
#include <hip/hip_runtime.h>

#define TT 8
#define HH 24
#define WW 24
#define NN 4608            // T*H*W
#define CIN 256
#define N3 6760            // padded volume 10*26*26 (bf16 transposed layout rows)
#define KDIM 6912          // 27 taps * 256 ci
#define BK 64
#define KTILES 108         // KDIM / BK
#define NSPLIT 4
#define KT_PER 27          // KTILES / NSPLIT

typedef short short8 __attribute__((ext_vector_type(8)));
typedef short short4v __attribute__((ext_vector_type(4)));
typedef float f32x4  __attribute__((ext_vector_type(4)));
typedef int   i32x4  __attribute__((ext_vector_type(4)));
typedef unsigned int u32x2 __attribute__((ext_vector_type(2)));

#define MFMA16 __builtin_amdgcn_mfma_f32_16x16x32_bf16

__device__ __forceinline__ short f2bf(float f) {       // RNE f32 -> bf16 bits
    unsigned u = __float_as_uint(f);
    unsigned r = u + 0x7fffu + ((u >> 16) & 1u);
    return (short)(r >> 16);
}

__device__ __forceinline__ int n3_of(int n) {          // interior n -> padded row
    int t = n / (HH * WW), r = n % (HH * WW), h = r / WW, w = r % WW;
    return ((t + 1) * 26 + (h + 1)) * 26 + (w + 1);
}

// async 16B global -> LDS (wave-uniform LDS base + lane*16; global addr per-lane)
__device__ __forceinline__ void gload16(const void* gsrc, void* lds) {
    __builtin_amdgcn_global_load_lds(
        (const __attribute__((address_space(1))) void*)gsrc,
        (__attribute__((address_space(3))) void*)lds, 16, 0, 0);
}

// ---------------------------------------------------------------- utility
// x[ci][n] -> xbf3[n3][ci] (bf16, 3D-zero-padded, transposed)
__global__ __launch_bounds__(256) void transpose_k(const float* __restrict__ x,
                                                   short* __restrict__ xbf3) {
    __shared__ float T[64][65];
    const int lane = threadIdx.x & 63, wave = threadIdx.x >> 6;
    const int n0 = blockIdx.x * 64, ci0 = blockIdx.y * 64;
    #pragma unroll
    for (int j = 0; j < 16; ++j) {
        int ci_l = wave * 16 + j;
        T[ci_l][lane] = x[(size_t)(ci0 + ci_l) * NN + n0 + lane];
    }
    __syncthreads();
    #pragma unroll
    for (int j = 0; j < 16; ++j) {
        int n_l = wave * 16 + j;
        xbf3[(size_t)n3_of(n0 + n_l) * 256 + ci0 + lane] = f2bf(T[lane][n_l]);
    }
}

// Pre-swizzled weight repack for linear global_load_lds staging.
// Layout: wrb_sw[y][kt][slot=row*8+g'][e], g' = (kk>>3) ^ (row&7), row=o&63, y=o>>6.
__global__ void repack_w_k(const float* __restrict__ w, short* __restrict__ dst, int Cout) {
    int o = blockIdx.x, ci = threadIdx.x;
    const int row = o & 63, y = o >> 6;
    #pragma unroll
    for (int k = 0; k < 27; ++k) {
        int K = k * 256 + ci;
        int kt = K >> 6, kk = K & 63;
        int g = (kk >> 3) ^ (row & 7), e = kk & 7;
        size_t idx = (((size_t)y * KTILES + kt) * 512 + row * 8 + g) * 8 + e;
        float v = (o < Cout) ? w[((size_t)o * CIN + ci) * 27 + k] : 0.f;
        dst[idx] = f2bf(v);
    }
}

// ---------------------------------------------------------------- corner table
// Per (k,n): 8 corner byte-offsets into xbf3 (clamped) + 8 masked weights. 64B record.
__global__ __launch_bounds__(256) void table_k(const float* __restrict__ offs,
                                               char* __restrict__ table) {
    const int id = blockIdx.x * 256 + threadIdx.x;     // 27*NN threads
    const int k = id / NN, n = id - k * NN;
    const int t = n / (HH * WW), r = n % (HH * WW), h = r / WW, w2 = r % WW;
    const int ki = k / 9, kj = (k % 9) / 3, kl = k % 3;
    const float pt = (float)(t  + ki - 1) + offs[(size_t)(k * 3 + 0) * NN + n];
    const float ph = (float)(h  + kj - 1) + offs[(size_t)(k * 3 + 1) * NN + n];
    const float pw = (float)(w2 + kl - 1) + offs[(size_t)(k * 3 + 2) * NN + n];
    const float ft = floorf(pt), fh = floorf(ph), fw = floorf(pw);
    const float at = pt - ft, ah = ph - fh, aw = pw - fw;
    const int it = (int)ft, ih = (int)fh, iw = (int)fw;

    i32x4 idx[2];
    f32x4 wgt[2];
    #pragma unroll
    for (int dt = 0; dt < 2; ++dt)
    #pragma unroll
    for (int dh = 0; dh < 2; ++dh)
    #pragma unroll
    for (int dw = 0; dw < 2; ++dw) {
        const int c = (dt * 2 + dh) * 2 + dw;
        const int ti = it + dt, hi = ih + dh, wi = iw + dw;
        const bool v = (ti >= 0) && (ti < TT) && (hi >= 0) && (hi < HH) && (wi >= 0) && (wi < WW);
        float wv = (dt ? at : 1.f - at) * (dh ? ah : 1.f - ah) * (dw ? aw : 1.f - aw);
        const int tc = min(max(ti, 0), TT - 1), hc = min(max(hi, 0), HH - 1), wc = min(max(wi, 0), WW - 1);
        const int r3 = ((tc + 1) * 26 + (hc + 1)) * 26 + (wc + 1);
        idx[c >> 2][c & 3] = r3 * 512;                 // byte offset of row in xbf3
        wgt[c >> 2][c & 3] = v ? wv : 0.f;
    }
    char* rec = table + (size_t)id * 64;
    *(i32x4*)(rec)      = idx[0];
    *(i32x4*)(rec + 16) = idx[1];
    *(f32x4*)(rec + 32) = wgt[0];
    *(f32x4*)(rec + 48) = wgt[1];
}

// ---------------------------------------------------------------- sampler
// S[k][n][ci] = bf16( sum_c w_c * xbf3[row_c][ci] ). One wave per n; lane = 4 ch.
__global__ __launch_bounds__(256) void sample_k(
    const short* __restrict__ xbf3, const char* __restrict__ table,
    short* __restrict__ S)
{
    const int k = blockIdx.y, n0 = blockIdx.x * 64;
    const int lane = threadIdx.x & 63, wave = threadIdx.x >> 6;
    const char* xb = (const char*)xbf3 + lane * 8;     // lane's 4 channels (8B)

    for (int i = 0; i < 16; ++i) {
        const int n = n0 + wave * 16 + i;
        const char* rec = table + ((size_t)k * NN + n) * 64;
        const i32x4 i03 = *(const i32x4*)(rec);
        const i32x4 i47 = *(const i32x4*)(rec + 16);
        const f32x4 w03 = *(const f32x4*)(rec + 32);
        const f32x4 w47 = *(const f32x4*)(rec + 48);

        float s0 = 0.f, s1 = 0.f, s2 = 0.f, s3 = 0.f;
        #pragma unroll
        for (int c = 0; c < 8; ++c) {
            const int  boff = (c < 4) ? i03[c & 3] : i47[c & 3];
            const float wv  = (c < 4) ? w03[c & 3] : w47[c & 3];
            const u32x2 v = *(const u32x2*)(xb + boff);
            s0 = fmaf(wv, __uint_as_float(v[0] << 16),          s0);
            s1 = fmaf(wv, __uint_as_float(v[0] & 0xffff0000u),  s1);
            s2 = fmaf(wv, __uint_as_float(v[1] << 16),          s2);
            s3 = fmaf(wv, __uint_as_float(v[1] & 0xffff0000u),  s3);
        }
        short4v o = { f2bf(s0), f2bf(s1), f2bf(s2), f2bf(s3) };
        *(short4v*)(S + ((size_t)k * NN + n) * 256 + lane * 4) = o;
    }
}

// ---------------------------------------------------------------- conv GEMM (split-K, async 2-phase pipeline)
template<int CP>
__global__ __launch_bounds__(256) void gemm_conv_sk(
    const short* __restrict__ src,            // bf16 [N3][256] plain
    const short* __restrict__ wrb_sw,         // bf16 pre-swizzled [y][kt][512][8]
    float* __restrict__ P)
{
    __shared__ short Ap[2][4096];
    __shared__ short Bw[2][4096];
    const int tid = threadIdx.x;
    const int l = tid & 63, w = tid >> 6;
    const int n0 = blockIdx.x * 64, co0 = blockIdx.y * 64, split = blockIdx.z;
    const int n_off = (w & 1) * 32, co_off = (w >> 1) * 32;
    const int lm = l & 15, lq = l >> 4;
    const int rswz = (lm & 7) << 3;
    const int kt0 = split * KT_PER;

    const int colA = 8 * ((l & 7) ^ (l >> 3));
    const int r3A0 = n3_of(n0 + w * 16 + (l >> 3));
    const int r3A1 = n3_of(n0 + w * 16 + 8 + (l >> 3));
    const short* bbase = wrb_sw + ((size_t)blockIdx.y * KTILES) * 4096 + (w * 2) * 512 + l * 8;

    f32x4 acc[2][2] = {};

    auto stage = [&](int buf, int kt) {
        const int k = kt >> 2, ci0 = (kt & 3) * 64;
        const int dt = k / 9 - 1, dh = (k % 9) / 3 - 1, dw = k % 3 - 1;
        const int d3 = (dt * 26 + dh) * 26 + dw;
        gload16(src + (size_t)(r3A0 + d3) * 256 + ci0 + colA, &Ap[buf][(w * 2) * 512]);
        gload16(src + (size_t)(r3A1 + d3) * 256 + ci0 + colA, &Ap[buf][(w * 2 + 1) * 512]);
        const short* b = bbase + (size_t)kt * 4096;
        gload16(b,       &Bw[buf][(w * 2) * 512]);
        gload16(b + 512, &Bw[buf][(w * 2 + 1) * 512]);
    };

    int cur = 0;
    stage(0, kt0);
    __syncthreads();
    for (int i = 0; i < KT_PER; ++i) {
        if (i + 1 < KT_PER) stage(cur ^ 1, kt0 + i + 1);
        #pragma unroll
        for (int ks = 0; ks < 2; ++ks) {
            const int c = (ks * 32 + lq * 8) ^ rswz;
            short8 a0 = *(const short8*)&Ap[cur][(n_off + lm) * 64 + c];
            short8 a1 = *(const short8*)&Ap[cur][(n_off + 16 + lm) * 64 + c];
            short8 b0 = *(const short8*)&Bw[cur][(co_off + lm) * 64 + c];
            short8 b1 = *(const short8*)&Bw[cur][(co_off + 16 + lm) * 64 + c];
            acc[0][0] = MFMA16(a0, b0, acc[0][0], 0, 0, 0);
            acc[0][1] = MFMA16(a0, b1, acc[0][1], 0, 0, 0);
            acc[1][0] = MFMA16(a1, b0, acc[1][0], 0, 0, 0);
            acc[1][1] = MFMA16(a1, b1, acc[1][1], 0, 0, 0);
        }
        __syncthreads();
        cur ^= 1;
    }
    #pragma unroll
    for (int fn = 0; fn < 2; ++fn)
    #pragma unroll
    for (int fc = 0; fc < 2; ++fc) {
        int co = co0 + co_off + fc * 16 + lm;
        int n = n0 + n_off + fn * 16 + lq * 4;
        *(f32x4*)(P + ((size_t)split * CP + co) * NN + n) = acc[fn][fc];
    }
}

// ---------------------------------------------------------------- deform GEMM (split-K, async 2-phase pipeline)
__global__ __launch_bounds__(256) void gemm_deform_sk(
    const short* __restrict__ S,              // bf16 [27][NN][256] plain
    const short* __restrict__ wrb_sw,
    float* __restrict__ P)
{
    __shared__ short Ap[2][4096];
    __shared__ short Bw[2][4096];
    const int tid = threadIdx.x;
    const int l = tid & 63, w = tid >> 6;
    const int n0 = blockIdx.x * 64, co0 = blockIdx.y * 64, split = blockIdx.z;
    const int n_off = (w & 1) * 32, co_off = (w >> 1) * 32;
    const int lm = l & 15, lq = l >> 4;
    const int rswz = (lm & 7) << 3;
    const int kt0 = split * KT_PER;

    const int colA = 8 * ((l & 7) ^ (l >> 3));
    const int rA0 = n0 + w * 16 + (l >> 3);
    const int rA1 = rA0 + 8;
    const short* bbase = wrb_sw + ((size_t)blockIdx.y * KTILES) * 4096 + (w * 2) * 512 + l * 8;

    f32x4 acc[2][2] = {};

    auto stage = [&](int buf, int kt) {
        const int k = kt >> 2, ci0 = (kt & 3) * 64;
        gload16(S + ((size_t)k * NN + rA0) * 256 + ci0 + colA, &Ap[buf][(w * 2) * 512]);
        gload16(S + ((size_t)k * NN + rA1) * 256 + ci0 + colA, &Ap[buf][(w * 2 + 1) * 512]);
        const short* b = bbase + (size_t)kt * 4096;
        gload16(b,       &Bw[buf][(w * 2) * 512]);
        gload16(b + 512, &Bw[buf][(w * 2 + 1) * 512]);
    };

    int cur = 0;
    stage(0, kt0);
    __syncthreads();
    for (int i = 0; i < KT_PER; ++i) {
        if (i + 1 < KT_PER) stage(cur ^ 1, kt0 + i + 1);
        #pragma unroll
        for (int ks = 0; ks < 2; ++ks) {
            const int c = (ks * 32 + lq * 8) ^ rswz;
            short8 a0 = *(const short8*)&Ap[cur][(n_off + lm) * 64 + c];
            short8 a1 = *(const short8*)&Ap[cur][(n_off + 16 + lm) * 64 + c];
            short8 b0 = *(const short8*)&Bw[cur][(co_off + lm) * 64 + c];
            short8 b1 = *(const short8*)&Bw[cur][(co_off + 16 + lm) * 64 + c];
            acc[0][0] = MFMA16(a0, b0, acc[0][0], 0, 0, 0);
            acc[0][1] = MFMA16(a0, b1, acc[0][1], 0, 0, 0);
            acc[1][0] = MFMA16(a1, b0, acc[1][0], 0, 0, 0);
            acc[1][1] = MFMA16(a1, b1, acc[1][1], 0, 0, 0);
        }
        __syncthreads();
        cur ^= 1;
    }
    #pragma unroll
    for (int fn = 0; fn < 2; ++fn)
    #pragma unroll
    for (int fc = 0; fc < 2; ++fc) {
        int co = co0 + co_off + fc * 16 + lm;
        int n = n0 + n_off + fn * 16 + lq * 4;
        *(f32x4*)(P + ((size_t)split * 256 + co) * NN + n) = acc[fn][fc];
    }
}

// ---------------------------------------------------------------- reduces
template<bool RELU>
__global__ __launch_bounds__(256) void reduce_k(
    const float* __restrict__ P, const float* __restrict__ bias,
    float* __restrict__ dst, int Cout, int CP)
{
    int id = blockIdx.x * 256 + threadIdx.x;
    int total = Cout * (NN / 4);
    if (id >= total) return;
    int co = id / (NN / 4), n4 = id - co * (NN / 4);
    const float* p0 = P + ((size_t)co) * NN + n4 * 4;
    f32x4 v = *(const f32x4*)p0;
    #pragma unroll
    for (int s = 1; s < NSPLIT; ++s) {
        f32x4 u = *(const f32x4*)(p0 + (size_t)s * CP * NN);
        #pragma unroll
        for (int q = 0; q < 4; ++q) v[q] += u[q];
    }
    float bv = bias[co];
    #pragma unroll
    for (int q = 0; q < 4; ++q) {
        float f = v[q] + bv;
        if (RELU) f = fmaxf(f, 0.f);
        v[q] = f;
    }
    *(f32x4*)(dst + (size_t)co * NN + n4 * 4) = v;
}

// bf16 3D-padded transposed output (h layers): bias+relu+cvt+transpose fused
__global__ __launch_bounds__(256) void reduce_bf3(
    const float* __restrict__ P, const float* __restrict__ bias,
    short* __restrict__ dst)
{
    __shared__ float T[64][65];
    const int lane = threadIdx.x & 63, wave = threadIdx.x >> 6;
    const int n0 = blockIdx.x * 64, co0 = blockIdx.y * 64;
    #pragma unroll
    for (int j = 0; j < 16; ++j) {
        int co_l = wave * 16 + j, co = co0 + co_l;
        const float* p0 = P + (size_t)co * NN + n0 + lane;
        float a = p0[0];
        #pragma unroll
        for (int s = 1; s < NSPLIT; ++s) a += p0[(size_t)s * 256 * NN];
        T[co_l][lane] = fmaxf(a + bias[co], 0.f);
    }
    __syncthreads();
    #pragma unroll
    for (int j = 0; j < 16; ++j) {
        int n_l = wave * 16 + j;
        dst[(size_t)n3_of(n0 + n_l) * 256 + co0 + lane] = f2bf(T[lane][n_l]);
    }
}

// ----------------------------------------------------------------
extern "C" void kernel_launch(void* const* d_in, const int* in_sizes, int n_in,
                              void* d_out, int out_size, void* d_ws, size_t ws_size,
                              hipStream_t stream)
{
    const float* x   = (const float*)d_in[0];
    const float* l1w = (const float*)d_in[1];
    const float* l1b = (const float*)d_in[2];
    const float* l2w = (const float*)d_in[3];
    const float* l2b = (const float*)d_in[4];
    const float* l3w = (const float*)d_in[5];
    const float* l3b = (const float*)d_in[6];
    const float* dfw = (const float*)d_in[7];
    const float* dfb = (const float*)d_in[8];
    const float* c3w = (const float*)d_in[9];
    const float* c3b = (const float*)d_in[10];
    float* out = (float*)d_out;

    // ---- workspace ----
    // Overlay region [0, 63.7MB): S (sample phase) over conv-phase-only buffers.
    char* base = (char*)d_ws;
    short* S    = (short*)base;                              // 27*NN*256*2 = 63,700,992
    short* h1b  = (short*)(base);                            // 3,461,120 each
    short* h2b  = (short*)(base + 3461120);
    short* h3b  = (short*)(base + 6922240);
    short* wrb1 = (short*)(base + 10383360);                 // 3,538,944 each
    short* wrb2 = (short*)(base + 13922304);
    short* wrb3 = (short*)(base + 17461248);
    short* wrbd = (short*)(base + 21000192);                 // 1,769,472 (ends 22.77MB < 63.7MB)
    // Non-overlaid region (live across the sample phase):
    char* q = base + 63700992;
    short* xbf3 = (short*)q; q += 3461120;                   // N3*256*2
    float* offs = (float*)q; q += 1492992;                   // 81*NN*4
    short* wrbc = (short*)q; q += 3538944;                   // 256*KDIM*2
    char*  tabl = q;         q += (size_t)27 * NN * 64;      // 7,962,624
    float* P    = (float*)q;                                 // 4*256*NN*4 = 18,874,368

    // zero pads (interiors fully overwritten each call)
    hipMemsetAsync(xbf3, 0, (size_t)N3 * 256 * 2, stream);
    hipMemsetAsync(h1b,  0, (size_t)3 * N3 * 256 * 2, stream);

    transpose_k<<<dim3(72, 4), dim3(256), 0, stream>>>(x, xbf3);
    repack_w_k<<<dim3(256), dim3(256), 0, stream>>>(l1w, wrb1, 256);
    repack_w_k<<<dim3(256), dim3(256), 0, stream>>>(l2w, wrb2, 256);
    repack_w_k<<<dim3(256), dim3(256), 0, stream>>>(l3w, wrb3, 256);
    repack_w_k<<<dim3(256), dim3(256), 0, stream>>>(c3w, wrbc, 256);
    repack_w_k<<<dim3(128), dim3(256), 0, stream>>>(dfw, wrbd, 81);

    const dim3 blk(256);
    const int rg81 = (81 * (NN / 4) + 255) / 256;     // 365
    const int rg256 = (256 * (NN / 4) + 255) / 256;   // 1152

    gemm_conv_sk<256><<<dim3(72, 4, NSPLIT), blk, 0, stream>>>(xbf3, wrb1, P);
    reduce_bf3       <<<dim3(72, 4),         blk, 0, stream>>>(P, l1b, h1b);
    gemm_conv_sk<256><<<dim3(72, 4, NSPLIT), blk, 0, stream>>>(h1b, wrb2, P);
    reduce_bf3       <<<dim3(72, 4),         blk, 0, stream>>>(P, l2b, h2b);
    gemm_conv_sk<256><<<dim3(72, 4, NSPLIT), blk, 0, stream>>>(h2b, wrb3, P);
    reduce_bf3       <<<dim3(72, 4),         blk, 0, stream>>>(P, l3b, h3b);
    gemm_conv_sk<128><<<dim3(72, 2, NSPLIT), blk, 0, stream>>>(h3b, wrbd, P);
    reduce_k<false>  <<<dim3(rg81),          blk, 0, stream>>>(P, dfb, offs, 81, 128);

    table_k <<<dim3(27 * NN / 256), blk, 0, stream>>>(offs, tabl);
    sample_k<<<dim3(72, 27),        blk, 0, stream>>>(xbf3, tabl, S);
    gemm_deform_sk<<<dim3(72, 4, NSPLIT), blk, 0, stream>>>(S, wrbc, P);
    reduce_k<false><<<dim3(rg256), blk, 0, stream>>>(P, c3b, out, 256, 256);
}

// Round 8
// 295.599 us; speedup vs baseline: 1.0402x; 1.0402x over previous
//
#include <hip/hip_runtime.h>

#define TT 8
#define HH 24
#define WW 24
#define NN 4608            // T*H*W
#define CIN 256
#define N3 6760            // padded volume 10*26*26 (bf16 transposed layout rows)
#define KDIM 6912          // 27 taps * 256 ci
#define BK 64
#define KTILES 108         // KDIM / BK
#define NSPLIT 4
#define KT_PER 27          // KTILES / NSPLIT

typedef short short8 __attribute__((ext_vector_type(8)));
typedef short short4v __attribute__((ext_vector_type(4)));
typedef float f32x4  __attribute__((ext_vector_type(4)));
typedef int   i32x4  __attribute__((ext_vector_type(4)));
typedef unsigned int u32x2 __attribute__((ext_vector_type(2)));

#define MFMA16 __builtin_amdgcn_mfma_f32_16x16x32_bf16

__device__ __forceinline__ short f2bf(float f) {       // RNE f32 -> bf16 bits
    unsigned u = __float_as_uint(f);
    unsigned r = u + 0x7fffu + ((u >> 16) & 1u);
    return (short)(r >> 16);
}

__device__ __forceinline__ int n3_of(int n) {          // interior n -> padded row
    int t = n / (HH * WW), r = n % (HH * WW), h = r / WW, w = r % WW;
    return ((t + 1) * 26 + (h + 1)) * 26 + (w + 1);
}

// async 16B global -> LDS (wave-uniform LDS base + lane*16; global addr per-lane)
__device__ __forceinline__ void gload16(const void* gsrc, void* lds) {
    __builtin_amdgcn_global_load_lds(
        (const __attribute__((address_space(1))) void*)gsrc,
        (__attribute__((address_space(3))) void*)lds, 16, 0, 0);
}

// ---------------------------------------------------------------- utility
// x[ci][n] -> xbf3[n3][ci] (bf16, 3D-zero-padded, transposed)
__global__ __launch_bounds__(256) void transpose_k(const float* __restrict__ x,
                                                   short* __restrict__ xbf3) {
    __shared__ float T[64][65];
    const int lane = threadIdx.x & 63, wave = threadIdx.x >> 6;
    const int n0 = blockIdx.x * 64, ci0 = blockIdx.y * 64;
    #pragma unroll
    for (int j = 0; j < 16; ++j) {
        int ci_l = wave * 16 + j;
        T[ci_l][lane] = x[(size_t)(ci0 + ci_l) * NN + n0 + lane];
    }
    __syncthreads();
    #pragma unroll
    for (int j = 0; j < 16; ++j) {
        int n_l = wave * 16 + j;
        xbf3[(size_t)n3_of(n0 + n_l) * 256 + ci0 + lane] = f2bf(T[lane][n_l]);
    }
}

// Pre-swizzled weight repack for linear global_load_lds staging.
// Layout: wrb_sw[y][kt][slot=row*8+g'][e], g' = (kk>>3) ^ (row&7), row=o&63, y=o>>6.
__global__ void repack_w_k(const float* __restrict__ w, short* __restrict__ dst, int Cout) {
    int o = blockIdx.x, ci = threadIdx.x;
    const int row = o & 63, y = o >> 6;
    #pragma unroll
    for (int k = 0; k < 27; ++k) {
        int K = k * 256 + ci;
        int kt = K >> 6, kk = K & 63;
        int g = (kk >> 3) ^ (row & 7), e = kk & 7;
        size_t idx = (((size_t)y * KTILES + kt) * 512 + row * 8 + g) * 8 + e;
        float v = (o < Cout) ? w[((size_t)o * CIN + ci) * 27 + k] : 0.f;
        dst[idx] = f2bf(v);
    }
}

// ---------------------------------------------------------------- corner table
// Per (k,n): 8 corner byte-offsets into xbf3 (clamped) + 8 masked weights. 64B record.
__global__ __launch_bounds__(256) void table_k(const float* __restrict__ offs,
                                               char* __restrict__ table) {
    const int id = blockIdx.x * 256 + threadIdx.x;     // 27*NN threads
    const int k = id / NN, n = id - k * NN;
    const int t = n / (HH * WW), r = n % (HH * WW), h = r / WW, w2 = r % WW;
    const int ki = k / 9, kj = (k % 9) / 3, kl = k % 3;
    const float pt = (float)(t  + ki - 1) + offs[(size_t)(k * 3 + 0) * NN + n];
    const float ph = (float)(h  + kj - 1) + offs[(size_t)(k * 3 + 1) * NN + n];
    const float pw = (float)(w2 + kl - 1) + offs[(size_t)(k * 3 + 2) * NN + n];
    const float ft = floorf(pt), fh = floorf(ph), fw = floorf(pw);
    const float at = pt - ft, ah = ph - fh, aw = pw - fw;
    const int it = (int)ft, ih = (int)fh, iw = (int)fw;

    i32x4 idx[2];
    f32x4 wgt[2];
    #pragma unroll
    for (int dt = 0; dt < 2; ++dt)
    #pragma unroll
    for (int dh = 0; dh < 2; ++dh)
    #pragma unroll
    for (int dw = 0; dw < 2; ++dw) {
        const int c = (dt * 2 + dh) * 2 + dw;
        const int ti = it + dt, hi = ih + dh, wi = iw + dw;
        const bool v = (ti >= 0) && (ti < TT) && (hi >= 0) && (hi < HH) && (wi >= 0) && (wi < WW);
        float wv = (dt ? at : 1.f - at) * (dh ? ah : 1.f - ah) * (dw ? aw : 1.f - aw);
        const int tc = min(max(ti, 0), TT - 1), hc = min(max(hi, 0), HH - 1), wc = min(max(wi, 0), WW - 1);
        const int r3 = ((tc + 1) * 26 + (hc + 1)) * 26 + (wc + 1);
        idx[c >> 2][c & 3] = r3 * 512;                 // byte offset of row in xbf3
        wgt[c >> 2][c & 3] = v ? wv : 0.f;
    }
    char* rec = table + (size_t)id * 64;
    *(i32x4*)(rec)      = idx[0];
    *(i32x4*)(rec + 16) = idx[1];
    *(f32x4*)(rec + 32) = wgt[0];
    *(f32x4*)(rec + 48) = wgt[1];
}

// ---------------------------------------------------------------- sampler
// S[k][n][ci] = bf16( sum_c w_c * xbf3[row_c][ci] ). One wave per n; lane = 4 ch.
// Records pre-staged in LDS (4KB/block); inner loop = LDS broadcast + 8 gathers.
__global__ __launch_bounds__(256) void sample_k(
    const short* __restrict__ xbf3, const char* __restrict__ table,
    short* __restrict__ S)
{
    __shared__ char recs[64 * 64];                     // 64 records x 64B
    const int k = blockIdx.y, n0 = blockIdx.x * 64;
    const int tid = threadIdx.x;
    {   // stage this block's 64 records: 256 threads x 16B, coalesced
        const char* src = table + ((size_t)k * NN + n0) * 64;
        *(i32x4*)&recs[tid * 16] = *(const i32x4*)(src + tid * 16);
    }
    __syncthreads();

    const int lane = tid & 63, wave = tid >> 6;
    const char* xb = (const char*)xbf3 + lane * 8;     // lane's 4 channels (8B)
    short* Sb = S + ((size_t)k * NN + n0 + wave * 16) * 256 + lane * 4;

    for (int i = 0; i < 16; i += 2) {
        const char* r0 = &recs[(wave * 16 + i) * 64];  // wave-uniform -> broadcast
        const char* r1 = r0 + 64;
        const i32x4 a03 = *(const i32x4*)(r0);
        const i32x4 a47 = *(const i32x4*)(r0 + 16);
        const f32x4 u03 = *(const f32x4*)(r0 + 32);
        const f32x4 u47 = *(const f32x4*)(r0 + 48);
        const i32x4 b03 = *(const i32x4*)(r1);
        const i32x4 b47 = *(const i32x4*)(r1 + 16);
        const f32x4 v03 = *(const f32x4*)(r1 + 32);
        const f32x4 v47 = *(const f32x4*)(r1 + 48);

        u32x2 ga[8], gb[8];                            // 16 independent gathers in flight
        #pragma unroll
        for (int c = 0; c < 4; ++c) {
            ga[c]     = *(const u32x2*)(xb + a03[c]);
            ga[c + 4] = *(const u32x2*)(xb + a47[c]);
            gb[c]     = *(const u32x2*)(xb + b03[c]);
            gb[c + 4] = *(const u32x2*)(xb + b47[c]);
        }

        float s0 = 0.f, s1 = 0.f, s2 = 0.f, s3 = 0.f;
        float t0 = 0.f, t1 = 0.f, t2 = 0.f, t3 = 0.f;
        #pragma unroll
        for (int c = 0; c < 8; ++c) {
            const float wa = (c < 4) ? u03[c & 3] : u47[c & 3];
            const float wb = (c < 4) ? v03[c & 3] : v47[c & 3];
            s0 = fmaf(wa, __uint_as_float(ga[c][0] << 16),         s0);
            s1 = fmaf(wa, __uint_as_float(ga[c][0] & 0xffff0000u), s1);
            s2 = fmaf(wa, __uint_as_float(ga[c][1] << 16),         s2);
            s3 = fmaf(wa, __uint_as_float(ga[c][1] & 0xffff0000u), s3);
            t0 = fmaf(wb, __uint_as_float(gb[c][0] << 16),         t0);
            t1 = fmaf(wb, __uint_as_float(gb[c][0] & 0xffff0000u), t1);
            t2 = fmaf(wb, __uint_as_float(gb[c][1] << 16),         t2);
            t3 = fmaf(wb, __uint_as_float(gb[c][1] & 0xffff0000u), t3);
        }
        short4v oa = { f2bf(s0), f2bf(s1), f2bf(s2), f2bf(s3) };
        short4v ob = { f2bf(t0), f2bf(t1), f2bf(t2), f2bf(t3) };
        *(short4v*)(Sb + (size_t)i * 256)       = oa;
        *(short4v*)(Sb + (size_t)(i + 1) * 256) = ob;
    }
}

// ---------------------------------------------------------------- conv GEMM (split-K, async 2-phase pipeline)
template<int CP>
__global__ __launch_bounds__(256) void gemm_conv_sk(
    const short* __restrict__ src,            // bf16 [N3][256] plain
    const short* __restrict__ wrb_sw,         // bf16 pre-swizzled [y][kt][512][8]
    float* __restrict__ P)
{
    __shared__ short Ap[2][4096];
    __shared__ short Bw[2][4096];
    const int tid = threadIdx.x;
    const int l = tid & 63, w = tid >> 6;
    const int n0 = blockIdx.x * 64, co0 = blockIdx.y * 64, split = blockIdx.z;
    const int n_off = (w & 1) * 32, co_off = (w >> 1) * 32;
    const int lm = l & 15, lq = l >> 4;
    const int rswz = (lm & 7) << 3;
    const int kt0 = split * KT_PER;

    const int colA = 8 * ((l & 7) ^ (l >> 3));
    const int r3A0 = n3_of(n0 + w * 16 + (l >> 3));
    const int r3A1 = n3_of(n0 + w * 16 + 8 + (l >> 3));
    const short* bbase = wrb_sw + ((size_t)blockIdx.y * KTILES) * 4096 + (w * 2) * 512 + l * 8;

    f32x4 acc[2][2] = {};

    auto stage = [&](int buf, int kt) {
        const int k = kt >> 2, ci0 = (kt & 3) * 64;
        const int dt = k / 9 - 1, dh = (k % 9) / 3 - 1, dw = k % 3 - 1;
        const int d3 = (dt * 26 + dh) * 26 + dw;
        gload16(src + (size_t)(r3A0 + d3) * 256 + ci0 + colA, &Ap[buf][(w * 2) * 512]);
        gload16(src + (size_t)(r3A1 + d3) * 256 + ci0 + colA, &Ap[buf][(w * 2 + 1) * 512]);
        const short* b = bbase + (size_t)kt * 4096;
        gload16(b,       &Bw[buf][(w * 2) * 512]);
        gload16(b + 512, &Bw[buf][(w * 2 + 1) * 512]);
    };

    int cur = 0;
    stage(0, kt0);
    __syncthreads();
    for (int i = 0; i < KT_PER; ++i) {
        if (i + 1 < KT_PER) stage(cur ^ 1, kt0 + i + 1);
        #pragma unroll
        for (int ks = 0; ks < 2; ++ks) {
            const int c = (ks * 32 + lq * 8) ^ rswz;
            short8 a0 = *(const short8*)&Ap[cur][(n_off + lm) * 64 + c];
            short8 a1 = *(const short8*)&Ap[cur][(n_off + 16 + lm) * 64 + c];
            short8 b0 = *(const short8*)&Bw[cur][(co_off + lm) * 64 + c];
            short8 b1 = *(const short8*)&Bw[cur][(co_off + 16 + lm) * 64 + c];
            acc[0][0] = MFMA16(a0, b0, acc[0][0], 0, 0, 0);
            acc[0][1] = MFMA16(a0, b1, acc[0][1], 0, 0, 0);
            acc[1][0] = MFMA16(a1, b0, acc[1][0], 0, 0, 0);
            acc[1][1] = MFMA16(a1, b1, acc[1][1], 0, 0, 0);
        }
        __syncthreads();
        cur ^= 1;
    }
    #pragma unroll
    for (int fn = 0; fn < 2; ++fn)
    #pragma unroll
    for (int fc = 0; fc < 2; ++fc) {
        int co = co0 + co_off + fc * 16 + lm;
        int n = n0 + n_off + fn * 16 + lq * 4;
        *(f32x4*)(P + ((size_t)split * CP + co) * NN + n) = acc[fn][fc];
    }
}

// ---------------------------------------------------------------- deform GEMM (split-K, async 2-phase pipeline)
__global__ __launch_bounds__(256) void gemm_deform_sk(
    const short* __restrict__ S,              // bf16 [27][NN][256] plain
    const short* __restrict__ wrb_sw,
    float* __restrict__ P)
{
    __shared__ short Ap[2][4096];
    __shared__ short Bw[2][4096];
    const int tid = threadIdx.x;
    const int l = tid & 63, w = tid >> 6;
    const int n0 = blockIdx.x * 64, co0 = blockIdx.y * 64, split = blockIdx.z;
    const int n_off = (w & 1) * 32, co_off = (w >> 1) * 32;
    const int lm = l & 15, lq = l >> 4;
    const int rswz = (lm & 7) << 3;
    const int kt0 = split * KT_PER;

    const int colA = 8 * ((l & 7) ^ (l >> 3));
    const int rA0 = n0 + w * 16 + (l >> 3);
    const int rA1 = rA0 + 8;
    const short* bbase = wrb_sw + ((size_t)blockIdx.y * KTILES) * 4096 + (w * 2) * 512 + l * 8;

    f32x4 acc[2][2] = {};

    auto stage = [&](int buf, int kt) {
        const int k = kt >> 2, ci0 = (kt & 3) * 64;
        gload16(S + ((size_t)k * NN + rA0) * 256 + ci0 + colA, &Ap[buf][(w * 2) * 512]);
        gload16(S + ((size_t)k * NN + rA1) * 256 + ci0 + colA, &Ap[buf][(w * 2 + 1) * 512]);
        const short* b = bbase + (size_t)kt * 4096;
        gload16(b,       &Bw[buf][(w * 2) * 512]);
        gload16(b + 512, &Bw[buf][(w * 2 + 1) * 512]);
    };

    int cur = 0;
    stage(0, kt0);
    __syncthreads();
    for (int i = 0; i < KT_PER; ++i) {
        if (i + 1 < KT_PER) stage(cur ^ 1, kt0 + i + 1);
        #pragma unroll
        for (int ks = 0; ks < 2; ++ks) {
            const int c = (ks * 32 + lq * 8) ^ rswz;
            short8 a0 = *(const short8*)&Ap[cur][(n_off + lm) * 64 + c];
            short8 a1 = *(const short8*)&Ap[cur][(n_off + 16 + lm) * 64 + c];
            short8 b0 = *(const short8*)&Bw[cur][(co_off + lm) * 64 + c];
            short8 b1 = *(const short8*)&Bw[cur][(co_off + 16 + lm) * 64 + c];
            acc[0][0] = MFMA16(a0, b0, acc[0][0], 0, 0, 0);
            acc[0][1] = MFMA16(a0, b1, acc[0][1], 0, 0, 0);
            acc[1][0] = MFMA16(a1, b0, acc[1][0], 0, 0, 0);
            acc[1][1] = MFMA16(a1, b1, acc[1][1], 0, 0, 0);
        }
        __syncthreads();
        cur ^= 1;
    }
    #pragma unroll
    for (int fn = 0; fn < 2; ++fn)
    #pragma unroll
    for (int fc = 0; fc < 2; ++fc) {
        int co = co0 + co_off + fc * 16 + lm;
        int n = n0 + n_off + fn * 16 + lq * 4;
        *(f32x4*)(P + ((size_t)split * 256 + co) * NN + n) = acc[fn][fc];
    }
}

// ---------------------------------------------------------------- reduces
template<bool RELU>
__global__ __launch_bounds__(256) void reduce_k(
    const float* __restrict__ P, const float* __restrict__ bias,
    float* __restrict__ dst, int Cout, int CP)
{
    int id = blockIdx.x * 256 + threadIdx.x;
    int total = Cout * (NN / 4);
    if (id >= total) return;
    int co = id / (NN / 4), n4 = id - co * (NN / 4);
    const float* p0 = P + ((size_t)co) * NN + n4 * 4;
    f32x4 v = *(const f32x4*)p0;
    #pragma unroll
    for (int s = 1; s < NSPLIT; ++s) {
        f32x4 u = *(const f32x4*)(p0 + (size_t)s * CP * NN);
        #pragma unroll
        for (int q = 0; q < 4; ++q) v[q] += u[q];
    }
    float bv = bias[co];
    #pragma unroll
    for (int q = 0; q < 4; ++q) {
        float f = v[q] + bv;
        if (RELU) f = fmaxf(f, 0.f);
        v[q] = f;
    }
    *(f32x4*)(dst + (size_t)co * NN + n4 * 4) = v;
}

// bf16 3D-padded transposed output (h layers): bias+relu+cvt+transpose fused
__global__ __launch_bounds__(256) void reduce_bf3(
    const float* __restrict__ P, const float* __restrict__ bias,
    short* __restrict__ dst)
{
    __shared__ float T[64][65];
    const int lane = threadIdx.x & 63, wave = threadIdx.x >> 6;
    const int n0 = blockIdx.x * 64, co0 = blockIdx.y * 64;
    #pragma unroll
    for (int j = 0; j < 16; ++j) {
        int co_l = wave * 16 + j, co = co0 + co_l;
        const float* p0 = P + (size_t)co * NN + n0 + lane;
        float a = p0[0];
        #pragma unroll
        for (int s = 1; s < NSPLIT; ++s) a += p0[(size_t)s * 256 * NN];
        T[co_l][lane] = fmaxf(a + bias[co], 0.f);
    }
    __syncthreads();
    #pragma unroll
    for (int j = 0; j < 16; ++j) {
        int n_l = wave * 16 + j;
        dst[(size_t)n3_of(n0 + n_l) * 256 + co0 + lane] = f2bf(T[lane][n_l]);
    }
}

// ----------------------------------------------------------------
extern "C" void kernel_launch(void* const* d_in, const int* in_sizes, int n_in,
                              void* d_out, int out_size, void* d_ws, size_t ws_size,
                              hipStream_t stream)
{
    const float* x   = (const float*)d_in[0];
    const float* l1w = (const float*)d_in[1];
    const float* l1b = (const float*)d_in[2];
    const float* l2w = (const float*)d_in[3];
    const float* l2b = (const float*)d_in[4];
    const float* l3w = (const float*)d_in[5];
    const float* l3b = (const float*)d_in[6];
    const float* dfw = (const float*)d_in[7];
    const float* dfb = (const float*)d_in[8];
    const float* c3w = (const float*)d_in[9];
    const float* c3b = (const float*)d_in[10];
    float* out = (float*)d_out;

    // ---- workspace ----
    // Overlay region [0, 63.7MB): S (sample phase) over conv-phase-only buffers.
    char* base = (char*)d_ws;
    short* S    = (short*)base;                              // 27*NN*256*2 = 63,700,992
    short* h1b  = (short*)(base);                            // 3,461,120 each
    short* h2b  = (short*)(base + 3461120);
    short* h3b  = (short*)(base + 6922240);
    short* wrb1 = (short*)(base + 10383360);                 // 3,538,944 each
    short* wrb2 = (short*)(base + 13922304);
    short* wrb3 = (short*)(base + 17461248);
    short* wrbd = (short*)(base + 21000192);                 // 1,769,472 (ends 22.77MB < 63.7MB)
    // Non-overlaid region (live across the sample phase):
    char* q = base + 63700992;
    short* xbf3 = (short*)q; q += 3461120;                   // N3*256*2
    float* offs = (float*)q; q += 1492992;                   // 81*NN*4
    short* wrbc = (short*)q; q += 3538944;                   // 256*KDIM*2
    char*  tabl = q;         q += (size_t)27 * NN * 64;      // 7,962,624
    float* P    = (float*)q;                                 // 4*256*NN*4 = 18,874,368

    // zero pads (interiors fully overwritten each call)
    hipMemsetAsync(xbf3, 0, (size_t)N3 * 256 * 2, stream);
    hipMemsetAsync(h1b,  0, (size_t)3 * N3 * 256 * 2, stream);

    transpose_k<<<dim3(72, 4), dim3(256), 0, stream>>>(x, xbf3);
    repack_w_k<<<dim3(256), dim3(256), 0, stream>>>(l1w, wrb1, 256);
    repack_w_k<<<dim3(256), dim3(256), 0, stream>>>(l2w, wrb2, 256);
    repack_w_k<<<dim3(256), dim3(256), 0, stream>>>(l3w, wrb3, 256);
    repack_w_k<<<dim3(256), dim3(256), 0, stream>>>(c3w, wrbc, 256);
    repack_w_k<<<dim3(128), dim3(256), 0, stream>>>(dfw, wrbd, 81);

    const dim3 blk(256);
    const int rg81 = (81 * (NN / 4) + 255) / 256;     // 365
    const int rg256 = (256 * (NN / 4) + 255) / 256;   // 1152

    gemm_conv_sk<256><<<dim3(72, 4, NSPLIT), blk, 0, stream>>>(xbf3, wrb1, P);
    reduce_bf3       <<<dim3(72, 4),         blk, 0, stream>>>(P, l1b, h1b);
    gemm_conv_sk<256><<<dim3(72, 4, NSPLIT), blk, 0, stream>>>(h1b, wrb2, P);
    reduce_bf3       <<<dim3(72, 4),         blk, 0, stream>>>(P, l2b, h2b);
    gemm_conv_sk<256><<<dim3(72, 4, NSPLIT), blk, 0, stream>>>(h2b, wrb3, P);
    reduce_bf3       <<<dim3(72, 4),         blk, 0, stream>>>(P, l3b, h3b);
    gemm_conv_sk<128><<<dim3(72, 2, NSPLIT), blk, 0, stream>>>(h3b, wrbd, P);
    reduce_k<false>  <<<dim3(rg81),          blk, 0, stream>>>(P, dfb, offs, 81, 128);

    table_k <<<dim3(27 * NN / 256), blk, 0, stream>>>(offs, tabl);
    sample_k<<<dim3(72, 27),        blk, 0, stream>>>(xbf3, tabl, S);
    gemm_deform_sk<<<dim3(72, 4, NSPLIT), blk, 0, stream>>>(S, wrbc, P);
    reduce_k<false><<<dim3(rg256), blk, 0, stream>>>(P, c3b, out, 256, 256);
}

// Round 9
// 257.341 us; speedup vs baseline: 1.1948x; 1.1487x over previous
//
#include <hip/hip_runtime.h>

#define TT 8
#define HH 24
#define WW 24
#define NN 4608            // T*H*W
#define CIN 256
#define N3 6760            // padded volume 10*26*26 (bf16 transposed layout rows)
#define KDIM 6912          // 27 taps * 256 ci
#define BK 64
#define KTILES 108         // KDIM / BK
#define NSPLIT 9
#define KT_PER 12          // KTILES / NSPLIT

typedef short short8 __attribute__((ext_vector_type(8)));
typedef short short4v __attribute__((ext_vector_type(4)));
typedef float f32x4  __attribute__((ext_vector_type(4)));
typedef int   i32x4  __attribute__((ext_vector_type(4)));
typedef unsigned int u32x2 __attribute__((ext_vector_type(2)));

#define MFMA16 __builtin_amdgcn_mfma_f32_16x16x32_bf16

__device__ __forceinline__ short f2bf(float f) {       // RNE f32 -> bf16 bits
    unsigned u = __float_as_uint(f);
    unsigned r = u + 0x7fffu + ((u >> 16) & 1u);
    return (short)(r >> 16);
}

__device__ __forceinline__ int n3_of(int n) {          // interior n -> padded row
    int t = n / (HH * WW), r = n % (HH * WW), h = r / WW, w = r % WW;
    return ((t + 1) * 26 + (h + 1)) * 26 + (w + 1);
}

// async 16B global -> LDS (wave-uniform LDS base + lane*16; global addr per-lane)
__device__ __forceinline__ void gload16(const void* gsrc, void* lds) {
    __builtin_amdgcn_global_load_lds(
        (const __attribute__((address_space(1))) void*)gsrc,
        (__attribute__((address_space(3))) void*)lds, 16, 0, 0);
}

// ---------------------------------------------------------------- utility
// x[ci][n] -> xbf3[n3][ci] (bf16, 3D-zero-padded, transposed)
__global__ __launch_bounds__(256) void transpose_k(const float* __restrict__ x,
                                                   short* __restrict__ xbf3) {
    __shared__ float T[64][65];
    const int lane = threadIdx.x & 63, wave = threadIdx.x >> 6;
    const int n0 = blockIdx.x * 64, ci0 = blockIdx.y * 64;
    #pragma unroll
    for (int j = 0; j < 16; ++j) {
        int ci_l = wave * 16 + j;
        T[ci_l][lane] = x[(size_t)(ci0 + ci_l) * NN + n0 + lane];
    }
    __syncthreads();
    #pragma unroll
    for (int j = 0; j < 16; ++j) {
        int n_l = wave * 16 + j;
        xbf3[(size_t)n3_of(n0 + n_l) * 256 + ci0 + lane] = f2bf(T[lane][n_l]);
    }
}

// Pre-swizzled weight repack for linear global_load_lds staging (128-row B tiles).
// Region (y, kt): 8192 shorts = B[row=o&127][64 kk]; element at row*64 + slot*8 + e,
// slot = (kk>>3) ^ (row&7).
__global__ void repack_w_k(const float* __restrict__ w, short* __restrict__ dst, int Cout) {
    int o = blockIdx.x, ci = threadIdx.x;
    const int row = o & 127, y = o >> 7;
    #pragma unroll
    for (int k = 0; k < 27; ++k) {
        int K = k * 256 + ci;
        int kt = K >> 6, kk = K & 63;
        int slot = (kk >> 3) ^ (row & 7), e = kk & 7;
        size_t idx = ((size_t)(y * KTILES + kt)) * 8192 + row * 64 + slot * 8 + e;
        float v = (o < Cout) ? w[((size_t)o * CIN + ci) * 27 + k] : 0.f;
        dst[idx] = f2bf(v);
    }
}

// ---------------------------------------------------------------- corner table
// Per (k,n): 8 corner byte-offsets into xbf3 (clamped) + 8 masked weights. 64B record.
__global__ __launch_bounds__(256) void table_k(const float* __restrict__ offs,
                                               char* __restrict__ table) {
    const int id = blockIdx.x * 256 + threadIdx.x;     // 27*NN threads
    const int k = id / NN, n = id - k * NN;
    const int t = n / (HH * WW), r = n % (HH * WW), h = r / WW, w2 = r % WW;
    const int ki = k / 9, kj = (k % 9) / 3, kl = k % 3;
    const float pt = (float)(t  + ki - 1) + offs[(size_t)(k * 3 + 0) * NN + n];
    const float ph = (float)(h  + kj - 1) + offs[(size_t)(k * 3 + 1) * NN + n];
    const float pw = (float)(w2 + kl - 1) + offs[(size_t)(k * 3 + 2) * NN + n];
    const float ft = floorf(pt), fh = floorf(ph), fw = floorf(pw);
    const float at = pt - ft, ah = ph - fh, aw = pw - fw;
    const int it = (int)ft, ih = (int)fh, iw = (int)fw;

    i32x4 idx[2];
    f32x4 wgt[2];
    #pragma unroll
    for (int dt = 0; dt < 2; ++dt)
    #pragma unroll
    for (int dh = 0; dh < 2; ++dh)
    #pragma unroll
    for (int dw = 0; dw < 2; ++dw) {
        const int c = (dt * 2 + dh) * 2 + dw;
        const int ti = it + dt, hi = ih + dh, wi = iw + dw;
        const bool v = (ti >= 0) && (ti < TT) && (hi >= 0) && (hi < HH) && (wi >= 0) && (wi < WW);
        float wv = (dt ? at : 1.f - at) * (dh ? ah : 1.f - ah) * (dw ? aw : 1.f - aw);
        const int tc = min(max(ti, 0), TT - 1), hc = min(max(hi, 0), HH - 1), wc = min(max(wi, 0), WW - 1);
        const int r3 = ((tc + 1) * 26 + (hc + 1)) * 26 + (wc + 1);
        idx[c >> 2][c & 3] = r3 * 512;                 // byte offset of row in xbf3
        wgt[c >> 2][c & 3] = v ? wv : 0.f;
    }
    char* rec = table + (size_t)id * 64;
    *(i32x4*)(rec)      = idx[0];
    *(i32x4*)(rec + 16) = idx[1];
    *(f32x4*)(rec + 32) = wgt[0];
    *(f32x4*)(rec + 48) = wgt[1];
}

// ---------------------------------------------------------------- sampler
// S[k][n][ci] = bf16( sum_c w_c * xbf3[row_c][ci] ). One wave per n; lane = 4 ch.
// Records pre-staged in LDS (4KB/block); inner loop = LDS broadcast + 8 gathers.
__global__ __launch_bounds__(256) void sample_k(
    const short* __restrict__ xbf3, const char* __restrict__ table,
    short* __restrict__ S)
{
    __shared__ char recs[64 * 64];                     // 64 records x 64B
    const int k = blockIdx.y, n0 = blockIdx.x * 64;
    const int tid = threadIdx.x;
    {   // stage this block's 64 records: 256 threads x 16B, coalesced
        const char* src = table + ((size_t)k * NN + n0) * 64;
        *(i32x4*)&recs[tid * 16] = *(const i32x4*)(src + tid * 16);
    }
    __syncthreads();

    const int lane = tid & 63, wave = tid >> 6;
    const char* xb = (const char*)xbf3 + lane * 8;     // lane's 4 channels (8B)
    short* Sb = S + ((size_t)k * NN + n0 + wave * 16) * 256 + lane * 4;

    for (int i = 0; i < 16; i += 2) {
        const char* r0 = &recs[(wave * 16 + i) * 64];  // wave-uniform -> broadcast
        const char* r1 = r0 + 64;
        const i32x4 a03 = *(const i32x4*)(r0);
        const i32x4 a47 = *(const i32x4*)(r0 + 16);
        const f32x4 u03 = *(const f32x4*)(r0 + 32);
        const f32x4 u47 = *(const f32x4*)(r0 + 48);
        const i32x4 b03 = *(const i32x4*)(r1);
        const i32x4 b47 = *(const i32x4*)(r1 + 16);
        const f32x4 v03 = *(const f32x4*)(r1 + 32);
        const f32x4 v47 = *(const f32x4*)(r1 + 48);

        u32x2 ga[8], gb[8];                            // 16 independent gathers in flight
        #pragma unroll
        for (int c = 0; c < 4; ++c) {
            ga[c]     = *(const u32x2*)(xb + a03[c]);
            ga[c + 4] = *(const u32x2*)(xb + a47[c]);
            gb[c]     = *(const u32x2*)(xb + b03[c]);
            gb[c + 4] = *(const u32x2*)(xb + b47[c]);
        }

        float s0 = 0.f, s1 = 0.f, s2 = 0.f, s3 = 0.f;
        float t0 = 0.f, t1 = 0.f, t2 = 0.f, t3 = 0.f;
        #pragma unroll
        for (int c = 0; c < 8; ++c) {
            const float wa = (c < 4) ? u03[c & 3] : u47[c & 3];
            const float wb = (c < 4) ? v03[c & 3] : v47[c & 3];
            s0 = fmaf(wa, __uint_as_float(ga[c][0] << 16),         s0);
            s1 = fmaf(wa, __uint_as_float(ga[c][0] & 0xffff0000u), s1);
            s2 = fmaf(wa, __uint_as_float(ga[c][1] << 16),         s2);
            s3 = fmaf(wa, __uint_as_float(ga[c][1] & 0xffff0000u), s3);
            t0 = fmaf(wb, __uint_as_float(gb[c][0] << 16),         t0);
            t1 = fmaf(wb, __uint_as_float(gb[c][0] & 0xffff0000u), t1);
            t2 = fmaf(wb, __uint_as_float(gb[c][1] << 16),         t2);
            t3 = fmaf(wb, __uint_as_float(gb[c][1] & 0xffff0000u), t3);
        }
        short4v oa = { f2bf(s0), f2bf(s1), f2bf(s2), f2bf(s3) };
        short4v ob = { f2bf(t0), f2bf(t1), f2bf(t2), f2bf(t3) };
        *(short4v*)(Sb + (size_t)i * 256)       = oa;
        *(short4v*)(Sb + (size_t)(i + 1) * 256) = ob;
    }
}

// ---------------------------------------------------------------- conv GEMM
// m97 geometry: 128x128 tile, 4 waves (2x2), 64x64 per wave (4x4 frags),
// BK=64, single-buffered LDS (32KB), 2 barriers/K-tile, split-K=9.
template<int CP>
__global__ __launch_bounds__(256, 3) void gemm_conv_sk(
    const short* __restrict__ src,            // bf16 [N3][256] plain
    const short* __restrict__ wrb_sw,         // bf16 pre-swizzled [y][kt][8192]
    float* __restrict__ P)
{
    __shared__ short Ap[8192];                // A [128 rows][64 kk] swizzled
    __shared__ short Bw[8192];                // B [128 rows][64 kk] swizzled
    const int tid = threadIdx.x;
    const int l = tid & 63, w = tid >> 6;
    const int n0 = blockIdx.x * 128, co0 = blockIdx.y * 128, split = blockIdx.z;
    const int wr = w >> 1, wc = w & 1;        // wave 2x2 grid
    const int lm = l & 15, lq = l >> 4;
    const int rswz = (lm & 7) << 3;
    const int kt0 = split * KT_PER;

    // staging: wave w covers rows w*32..w*32+31 (4 loads x 8 rows each)
    const int colA = 8 * ((l & 7) ^ ((l >> 3) & 7));
    int r3[4];
    #pragma unroll
    for (int j = 0; j < 4; ++j)
        r3[j] = n3_of(n0 + w * 32 + j * 8 + (l >> 3));
    const short* bbase = wrb_sw + ((size_t)blockIdx.y * KTILES) * 8192 + (w * 4) * 512 + l * 8;

    f32x4 acc[4][4] = {};

    for (int i = 0; i < KT_PER; ++i) {
        const int kt = kt0 + i;
        const int k = kt >> 2, ci0 = (kt & 3) * 64;
        const int dt = k / 9 - 1, dh = (k % 9) / 3 - 1, dw = k % 3 - 1;
        const int d3 = (dt * 26 + dh) * 26 + dw;
        #pragma unroll
        for (int j = 0; j < 4; ++j)
            gload16(src + (size_t)(r3[j] + d3) * 256 + ci0 + colA, &Ap[(w * 4 + j) * 512]);
        const short* b = bbase + (size_t)kt * 8192;
        #pragma unroll
        for (int j = 0; j < 4; ++j)
            gload16(b + j * 512, &Bw[(w * 4 + j) * 512]);
        __syncthreads();                       // drains vmcnt(0): tile staged
        #pragma unroll
        for (int ks = 0; ks < 2; ++ks) {
            const int c = (ks * 32 + lq * 8) ^ rswz;
            short8 a[4], bf[4];
            #pragma unroll
            for (int m = 0; m < 4; ++m)
                a[m] = *(const short8*)&Ap[(wr * 64 + m * 16 + lm) * 64 + c];
            #pragma unroll
            for (int nb = 0; nb < 4; ++nb)
                bf[nb] = *(const short8*)&Bw[(wc * 64 + nb * 16 + lm) * 64 + c];
            #pragma unroll
            for (int m = 0; m < 4; ++m)
            #pragma unroll
            for (int nb = 0; nb < 4; ++nb)
                acc[m][nb] = MFMA16(a[m], bf[nb], acc[m][nb], 0, 0, 0);
        }
        __syncthreads();                       // all reads done before next stage
    }
    #pragma unroll
    for (int m = 0; m < 4; ++m)
    #pragma unroll
    for (int nb = 0; nb < 4; ++nb) {
        int co = co0 + wc * 64 + nb * 16 + lm;
        int n = n0 + wr * 64 + m * 16 + lq * 4;
        *(f32x4*)(P + ((size_t)split * CP + co) * NN + n) = acc[m][nb];
    }
}

// ---------------------------------------------------------------- deform GEMM (same geometry)
__global__ __launch_bounds__(256, 3) void gemm_deform_sk(
    const short* __restrict__ S,              // bf16 [27][NN][256] plain
    const short* __restrict__ wrb_sw,
    float* __restrict__ P)
{
    __shared__ short Ap[8192];
    __shared__ short Bw[8192];
    const int tid = threadIdx.x;
    const int l = tid & 63, w = tid >> 6;
    const int n0 = blockIdx.x * 128, co0 = blockIdx.y * 128, split = blockIdx.z;
    const int wr = w >> 1, wc = w & 1;
    const int lm = l & 15, lq = l >> 4;
    const int rswz = (lm & 7) << 3;
    const int kt0 = split * KT_PER;

    const int colA = 8 * ((l & 7) ^ ((l >> 3) & 7));
    int rA[4];
    #pragma unroll
    for (int j = 0; j < 4; ++j)
        rA[j] = n0 + w * 32 + j * 8 + (l >> 3);
    const short* bbase = wrb_sw + ((size_t)blockIdx.y * KTILES) * 8192 + (w * 4) * 512 + l * 8;

    f32x4 acc[4][4] = {};

    for (int i = 0; i < KT_PER; ++i) {
        const int kt = kt0 + i;
        const int k = kt >> 2, ci0 = (kt & 3) * 64;
        #pragma unroll
        for (int j = 0; j < 4; ++j)
            gload16(S + ((size_t)k * NN + rA[j]) * 256 + ci0 + colA, &Ap[(w * 4 + j) * 512]);
        const short* b = bbase + (size_t)kt * 8192;
        #pragma unroll
        for (int j = 0; j < 4; ++j)
            gload16(b + j * 512, &Bw[(w * 4 + j) * 512]);
        __syncthreads();
        #pragma unroll
        for (int ks = 0; ks < 2; ++ks) {
            const int c = (ks * 32 + lq * 8) ^ rswz;
            short8 a[4], bf[4];
            #pragma unroll
            for (int m = 0; m < 4; ++m)
                a[m] = *(const short8*)&Ap[(wr * 64 + m * 16 + lm) * 64 + c];
            #pragma unroll
            for (int nb = 0; nb < 4; ++nb)
                bf[nb] = *(const short8*)&Bw[(wc * 64 + nb * 16 + lm) * 64 + c];
            #pragma unroll
            for (int m = 0; m < 4; ++m)
            #pragma unroll
            for (int nb = 0; nb < 4; ++nb)
                acc[m][nb] = MFMA16(a[m], bf[nb], acc[m][nb], 0, 0, 0);
        }
        __syncthreads();
    }
    #pragma unroll
    for (int m = 0; m < 4; ++m)
    #pragma unroll
    for (int nb = 0; nb < 4; ++nb) {
        int co = co0 + wc * 64 + nb * 16 + lm;
        int n = n0 + wr * 64 + m * 16 + lq * 4;
        *(f32x4*)(P + ((size_t)split * 256 + co) * NN + n) = acc[m][nb];
    }
}

// ---------------------------------------------------------------- reduces
template<bool RELU>
__global__ __launch_bounds__(256) void reduce_k(
    const float* __restrict__ P, const float* __restrict__ bias,
    float* __restrict__ dst, int Cout, int CP)
{
    int id = blockIdx.x * 256 + threadIdx.x;
    int total = Cout * (NN / 4);
    if (id >= total) return;
    int co = id / (NN / 4), n4 = id - co * (NN / 4);
    const float* p0 = P + ((size_t)co) * NN + n4 * 4;
    f32x4 v = *(const f32x4*)p0;
    #pragma unroll
    for (int s = 1; s < NSPLIT; ++s) {
        f32x4 u = *(const f32x4*)(p0 + (size_t)s * CP * NN);
        #pragma unroll
        for (int q = 0; q < 4; ++q) v[q] += u[q];
    }
    float bv = bias[co];
    #pragma unroll
    for (int q = 0; q < 4; ++q) {
        float f = v[q] + bv;
        if (RELU) f = fmaxf(f, 0.f);
        v[q] = f;
    }
    *(f32x4*)(dst + (size_t)co * NN + n4 * 4) = v;
}

// bf16 3D-padded transposed output (h layers): bias+relu+cvt+transpose fused
__global__ __launch_bounds__(256) void reduce_bf3(
    const float* __restrict__ P, const float* __restrict__ bias,
    short* __restrict__ dst)
{
    __shared__ float T[64][65];
    const int lane = threadIdx.x & 63, wave = threadIdx.x >> 6;
    const int n0 = blockIdx.x * 64, co0 = blockIdx.y * 64;
    #pragma unroll
    for (int j = 0; j < 16; ++j) {
        int co_l = wave * 16 + j, co = co0 + co_l;
        const float* p0 = P + (size_t)co * NN + n0 + lane;
        float a = p0[0];
        #pragma unroll
        for (int s = 1; s < NSPLIT; ++s) a += p0[(size_t)s * 256 * NN];
        T[co_l][lane] = fmaxf(a + bias[co], 0.f);
    }
    __syncthreads();
    #pragma unroll
    for (int j = 0; j < 16; ++j) {
        int n_l = wave * 16 + j;
        dst[(size_t)n3_of(n0 + n_l) * 256 + co0 + lane] = f2bf(T[lane][n_l]);
    }
}

// ----------------------------------------------------------------
extern "C" void kernel_launch(void* const* d_in, const int* in_sizes, int n_in,
                              void* d_out, int out_size, void* d_ws, size_t ws_size,
                              hipStream_t stream)
{
    const float* x   = (const float*)d_in[0];
    const float* l1w = (const float*)d_in[1];
    const float* l1b = (const float*)d_in[2];
    const float* l2w = (const float*)d_in[3];
    const float* l2b = (const float*)d_in[4];
    const float* l3w = (const float*)d_in[5];
    const float* l3b = (const float*)d_in[6];
    const float* dfw = (const float*)d_in[7];
    const float* dfb = (const float*)d_in[8];
    const float* c3w = (const float*)d_in[9];
    const float* c3b = (const float*)d_in[10];
    float* out = (float*)d_out;

    // ---- workspace ----
    // Overlay region [0, 63.7MB): S (sample phase) over conv-phase-only buffers.
    char* base = (char*)d_ws;
    short* S    = (short*)base;                              // 27*NN*256*2 = 63,700,992
    short* h1b  = (short*)(base);                            // 3,461,120 each
    short* h2b  = (short*)(base + 3461120);
    short* h3b  = (short*)(base + 6922240);
    short* wrb1 = (short*)(base + 10383360);                 // 3,538,944 each
    short* wrb2 = (short*)(base + 13922304);
    short* wrb3 = (short*)(base + 17461248);
    short* wrbd = (short*)(base + 21000192);                 // 1,769,472 (ends 22.77MB < 63.7MB)
    // Non-overlaid region (live across the sample phase):
    char* q = base + 63700992;
    short* xbf3 = (short*)q; q += 3461120;                   // N3*256*2
    float* offs = (float*)q; q += 1492992;                   // 81*NN*4
    short* wrbc = (short*)q; q += 3538944;                   // 256*KDIM*2
    float* P    = (float*)q;                                 // 9*256*NN*4 = 42,467,328
    // tabl overlays P: written after offs-reduce (P dead), dead before deform GEMM.
    char*  tabl = (char*)P;                                  // 27*NN*64 = 7,962,624 <= P size

    // zero pads (interiors fully overwritten each call)
    hipMemsetAsync(xbf3, 0, (size_t)N3 * 256 * 2, stream);
    hipMemsetAsync(h1b,  0, (size_t)3 * N3 * 256 * 2, stream);

    transpose_k<<<dim3(72, 4), dim3(256), 0, stream>>>(x, xbf3);
    repack_w_k<<<dim3(256), dim3(256), 0, stream>>>(l1w, wrb1, 256);
    repack_w_k<<<dim3(256), dim3(256), 0, stream>>>(l2w, wrb2, 256);
    repack_w_k<<<dim3(256), dim3(256), 0, stream>>>(l3w, wrb3, 256);
    repack_w_k<<<dim3(256), dim3(256), 0, stream>>>(c3w, wrbc, 256);
    repack_w_k<<<dim3(128), dim3(256), 0, stream>>>(dfw, wrbd, 81);

    const dim3 blk(256);
    const int rg81 = (81 * (NN / 4) + 255) / 256;     // 365
    const int rg256 = (256 * (NN / 4) + 255) / 256;   // 1152

    gemm_conv_sk<256><<<dim3(36, 2, NSPLIT), blk, 0, stream>>>(xbf3, wrb1, P);
    reduce_bf3       <<<dim3(72, 4),         blk, 0, stream>>>(P, l1b, h1b);
    gemm_conv_sk<256><<<dim3(36, 2, NSPLIT), blk, 0, stream>>>(h1b, wrb2, P);
    reduce_bf3       <<<dim3(72, 4),         blk, 0, stream>>>(P, l2b, h2b);
    gemm_conv_sk<256><<<dim3(36, 2, NSPLIT), blk, 0, stream>>>(h2b, wrb3, P);
    reduce_bf3       <<<dim3(72, 4),         blk, 0, stream>>>(P, l3b, h3b);
    gemm_conv_sk<128><<<dim3(36, 1, NSPLIT), blk, 0, stream>>>(h3b, wrbd, P);
    reduce_k<false>  <<<dim3(rg81),          blk, 0, stream>>>(P, dfb, offs, 81, 128);

    table_k <<<dim3(27 * NN / 256), blk, 0, stream>>>(offs, tabl);
    sample_k<<<dim3(72, 27),        blk, 0, stream>>>(xbf3, tabl, S);
    gemm_deform_sk<<<dim3(36, 2, NSPLIT), blk, 0, stream>>>(S, wrbc, P);
    reduce_k<false><<<dim3(rg256), blk, 0, stream>>>(P, c3b, out, 256, 256);
}

// Round 10
// 231.422 us; speedup vs baseline: 1.3287x; 1.1120x over previous
//
#include <hip/hip_runtime.h>

#define TT 8
#define HH 24
#define WW 24
#define NN 4608            // T*H*W
#define CIN 256
#define N3 6760            // padded volume 10*26*26 (bf16 transposed layout rows)
#define KDIM 6912          // 27 taps * 256 ci
#define BK 64
#define KTILES 108         // KDIM / BK
#define NSPLIT 6
#define KT_PER 18          // KTILES / NSPLIT

typedef short short8 __attribute__((ext_vector_type(8)));
typedef short short4v __attribute__((ext_vector_type(4)));
typedef float f32x4  __attribute__((ext_vector_type(4)));
typedef int   i32x4  __attribute__((ext_vector_type(4)));
typedef unsigned int u32x4 __attribute__((ext_vector_type(4)));

#define MFMA16 __builtin_amdgcn_mfma_f32_16x16x32_bf16

__device__ __forceinline__ short f2bf(float f) {       // RNE f32 -> bf16 bits
    unsigned u = __float_as_uint(f);
    unsigned r = u + 0x7fffu + ((u >> 16) & 1u);
    return (short)(r >> 16);
}

__device__ __forceinline__ int n3_of(int n) {          // interior n -> padded row
    int t = n / (HH * WW), r = n % (HH * WW), h = r / WW, w = r % WW;
    return ((t + 1) * 26 + (h + 1)) * 26 + (w + 1);
}

// async 16B global -> LDS (wave-uniform LDS base + lane*16; global addr per-lane)
__device__ __forceinline__ void gload16(const void* gsrc, void* lds) {
    __builtin_amdgcn_global_load_lds(
        (const __attribute__((address_space(1))) void*)gsrc,
        (__attribute__((address_space(3))) void*)lds, 16, 0, 0);
}

// ---------------------------------------------------------------- utility
// x[ci][n] -> xbf3[n3][ci] (bf16, 3D-zero-padded, transposed)
__global__ __launch_bounds__(256) void transpose_k(const float* __restrict__ x,
                                                   short* __restrict__ xbf3) {
    __shared__ float T[64][65];
    const int lane = threadIdx.x & 63, wave = threadIdx.x >> 6;
    const int n0 = blockIdx.x * 64, ci0 = blockIdx.y * 64;
    #pragma unroll
    for (int j = 0; j < 16; ++j) {
        int ci_l = wave * 16 + j;
        T[ci_l][lane] = x[(size_t)(ci0 + ci_l) * NN + n0 + lane];
    }
    __syncthreads();
    #pragma unroll
    for (int j = 0; j < 16; ++j) {
        int n_l = wave * 16 + j;
        xbf3[(size_t)n3_of(n0 + n_l) * 256 + ci0 + lane] = f2bf(T[lane][n_l]);
    }
}

// Pre-swizzled weight repack for linear global_load_lds staging (128-row B tiles).
// Region (y, kt): 8192 shorts = B[row=o&127][64 kk]; element at row*64 + slot*8 + e,
// slot = (kk>>3) ^ (row&7).
__global__ void repack_w_k(const float* __restrict__ w, short* __restrict__ dst, int Cout) {
    int o = blockIdx.x, ci = threadIdx.x;
    const int row = o & 127, y = o >> 7;
    #pragma unroll
    for (int k = 0; k < 27; ++k) {
        int K = k * 256 + ci;
        int kt = K >> 6, kk = K & 63;
        int slot = (kk >> 3) ^ (row & 7), e = kk & 7;
        size_t idx = ((size_t)(y * KTILES + kt)) * 8192 + row * 64 + slot * 8 + e;
        float v = (o < Cout) ? w[((size_t)o * CIN + ci) * 27 + k] : 0.f;
        dst[idx] = f2bf(v);
    }
}

// ---------------------------------------------------------------- sampler
// S[k][n][ci] = bf16( sum_c w_c * xbf3[row_c][ci] ).
// Records (8 corner row byte-offsets + 8 masked weights) computed in-block into
// LDS; half-wave per n: 32 lanes x 8ch (16B dwordx4 gathers), 4 n per iter.
__global__ __launch_bounds__(256) void sample_k(
    const short* __restrict__ xbf3, const float* __restrict__ offs,
    short* __restrict__ S)
{
    __shared__ char recs[64 * 64];                     // 64 records x 64B
    const int k = blockIdx.y, n0 = blockIdx.x * 64;
    const int tid = threadIdx.x;

    if (tid < 64) {                                    // compute this block's records
        const int n = n0 + tid;
        const int t = n / (HH * WW), r = n % (HH * WW), h = r / WW, w2 = r % WW;
        const int ki = k / 9, kj = (k % 9) / 3, kl = k % 3;
        const float pt = (float)(t  + ki - 1) + offs[(size_t)(k * 3 + 0) * NN + n];
        const float ph = (float)(h  + kj - 1) + offs[(size_t)(k * 3 + 1) * NN + n];
        const float pw = (float)(w2 + kl - 1) + offs[(size_t)(k * 3 + 2) * NN + n];
        const float ft = floorf(pt), fh = floorf(ph), fw = floorf(pw);
        const float at = pt - ft, ah = ph - fh, aw = pw - fw;
        const int it = (int)ft, ih = (int)fh, iw = (int)fw;
        i32x4 idx[2]; f32x4 wgt[2];
        #pragma unroll
        for (int dt = 0; dt < 2; ++dt)
        #pragma unroll
        for (int dh = 0; dh < 2; ++dh)
        #pragma unroll
        for (int dw = 0; dw < 2; ++dw) {
            const int c = (dt * 2 + dh) * 2 + dw;
            const int ti = it + dt, hi = ih + dh, wi = iw + dw;
            const bool v = (ti >= 0) && (ti < TT) && (hi >= 0) && (hi < HH) && (wi >= 0) && (wi < WW);
            float wv = (dt ? at : 1.f - at) * (dh ? ah : 1.f - ah) * (dw ? aw : 1.f - aw);
            const int tc = min(max(ti, 0), TT - 1), hc = min(max(hi, 0), HH - 1), wc = min(max(wi, 0), WW - 1);
            const int r3 = ((tc + 1) * 26 + (hc + 1)) * 26 + (wc + 1);
            idx[c >> 2][c & 3] = r3 * 512;             // byte offset of row in xbf3
            wgt[c >> 2][c & 3] = v ? wv : 0.f;
        }
        char* rec = &recs[tid * 64];
        *(i32x4*)(rec)      = idx[0];
        *(i32x4*)(rec + 16) = idx[1];
        *(f32x4*)(rec + 32) = wgt[0];
        *(f32x4*)(rec + 48) = wgt[1];
    }
    __syncthreads();

    const int lane = tid & 63, wave = tid >> 6;
    const int half = lane >> 5, lch = lane & 31;       // half-wave owns one n; 8 ch/lane
    const char* xb = (const char*)xbf3 + lch * 16;
    short* Sk = S + (size_t)k * NN * 256 + lch * 8;

    for (int i = 0; i < 16; i += 4) {                  // 4 n per iter (2 per half-wave)
        const int na = wave * 16 + i + half;           // local n index of this half
        const int nb = na + 2;
        const char* ra = &recs[na * 64];
        const char* rb = &recs[nb * 64];
        const i32x4 ia0 = *(const i32x4*)(ra);
        const i32x4 ia1 = *(const i32x4*)(ra + 16);
        const f32x4 wa0 = *(const f32x4*)(ra + 32);
        const f32x4 wa1 = *(const f32x4*)(ra + 48);
        const i32x4 ib0 = *(const i32x4*)(rb);
        const i32x4 ib1 = *(const i32x4*)(rb + 16);
        const f32x4 wb0 = *(const f32x4*)(rb + 32);
        const f32x4 wb1 = *(const f32x4*)(rb + 48);

        u32x4 ga[8], gb[8];                            // 16 x 16B gathers in flight
        #pragma unroll
        for (int c = 0; c < 4; ++c) {
            ga[c]     = *(const u32x4*)(xb + ia0[c]);
            ga[c + 4] = *(const u32x4*)(xb + ia1[c]);
            gb[c]     = *(const u32x4*)(xb + ib0[c]);
            gb[c + 4] = *(const u32x4*)(xb + ib1[c]);
        }

        float sa[8] = {}, sb[8] = {};
        #pragma unroll
        for (int c = 0; c < 8; ++c) {
            const float va = (c < 4) ? wa0[c & 3] : wa1[c & 3];
            const float vb = (c < 4) ? wb0[c & 3] : wb1[c & 3];
            #pragma unroll
            for (int j = 0; j < 4; ++j) {
                sa[2*j]   = fmaf(va, __uint_as_float(ga[c][j] << 16),         sa[2*j]);
                sa[2*j+1] = fmaf(va, __uint_as_float(ga[c][j] & 0xffff0000u), sa[2*j+1]);
                sb[2*j]   = fmaf(vb, __uint_as_float(gb[c][j] << 16),         sb[2*j]);
                sb[2*j+1] = fmaf(vb, __uint_as_float(gb[c][j] & 0xffff0000u), sb[2*j+1]);
            }
        }
        short8 oa, ob;
        #pragma unroll
        for (int m = 0; m < 8; ++m) { oa[m] = f2bf(sa[m]); ob[m] = f2bf(sb[m]); }
        *(short8*)(Sk + (size_t)(n0 + na) * 256) = oa;
        *(short8*)(Sk + (size_t)(n0 + nb) * 256) = ob;
    }
}

// ---------------------------------------------------------------- conv GEMM
// m97 geometry: 128x128 tile, 4 waves (2x2), 64x64 per wave (4x4 frags),
// BK=64, single-buffered LDS (32KB), 2 barriers/K-tile, split-K=6.
template<int CP>
__global__ __launch_bounds__(256, 3) void gemm_conv_sk(
    const short* __restrict__ src,            // bf16 [N3][256] plain
    const short* __restrict__ wrb_sw,         // bf16 pre-swizzled [y][kt][8192]
    float* __restrict__ P)
{
    __shared__ short Ap[8192];                // A [128 rows][64 kk] swizzled
    __shared__ short Bw[8192];                // B [128 rows][64 kk] swizzled
    const int tid = threadIdx.x;
    const int l = tid & 63, w = tid >> 6;
    const int n0 = blockIdx.x * 128, co0 = blockIdx.y * 128, split = blockIdx.z;
    const int wr = w >> 1, wc = w & 1;        // wave 2x2 grid
    const int lm = l & 15, lq = l >> 4;
    const int rswz = (lm & 7) << 3;
    const int kt0 = split * KT_PER;

    // staging: wave w covers rows w*32..w*32+31 (4 loads x 8 rows each)
    const int colA = 8 * ((l & 7) ^ ((l >> 3) & 7));
    int r3[4];
    #pragma unroll
    for (int j = 0; j < 4; ++j)
        r3[j] = n3_of(n0 + w * 32 + j * 8 + (l >> 3));
    const short* bbase = wrb_sw + ((size_t)blockIdx.y * KTILES) * 8192 + (w * 4) * 512 + l * 8;

    f32x4 acc[4][4] = {};

    for (int i = 0; i < KT_PER; ++i) {
        const int kt = kt0 + i;
        const int k = kt >> 2, ci0 = (kt & 3) * 64;
        const int dt = k / 9 - 1, dh = (k % 9) / 3 - 1, dw = k % 3 - 1;
        const int d3 = (dt * 26 + dh) * 26 + dw;
        #pragma unroll
        for (int j = 0; j < 4; ++j)
            gload16(src + (size_t)(r3[j] + d3) * 256 + ci0 + colA, &Ap[(w * 4 + j) * 512]);
        const short* b = bbase + (size_t)kt * 8192;
        #pragma unroll
        for (int j = 0; j < 4; ++j)
            gload16(b + j * 512, &Bw[(w * 4 + j) * 512]);
        __syncthreads();                       // drains vmcnt(0): tile staged
        #pragma unroll
        for (int ks = 0; ks < 2; ++ks) {
            const int c = (ks * 32 + lq * 8) ^ rswz;
            short8 a[4], bf[4];
            #pragma unroll
            for (int m = 0; m < 4; ++m)
                a[m] = *(const short8*)&Ap[(wr * 64 + m * 16 + lm) * 64 + c];
            #pragma unroll
            for (int nb = 0; nb < 4; ++nb)
                bf[nb] = *(const short8*)&Bw[(wc * 64 + nb * 16 + lm) * 64 + c];
            #pragma unroll
            for (int m = 0; m < 4; ++m)
            #pragma unroll
            for (int nb = 0; nb < 4; ++nb)
                acc[m][nb] = MFMA16(a[m], bf[nb], acc[m][nb], 0, 0, 0);
        }
        __syncthreads();                       // all reads done before next stage
    }
    #pragma unroll
    for (int m = 0; m < 4; ++m)
    #pragma unroll
    for (int nb = 0; nb < 4; ++nb) {
        int co = co0 + wc * 64 + nb * 16 + lm;
        int n = n0 + wr * 64 + m * 16 + lq * 4;
        *(f32x4*)(P + ((size_t)split * CP + co) * NN + n) = acc[m][nb];
    }
}

// ---------------------------------------------------------------- deform GEMM (same geometry)
__global__ __launch_bounds__(256, 3) void gemm_deform_sk(
    const short* __restrict__ S,              // bf16 [27][NN][256] plain
    const short* __restrict__ wrb_sw,
    float* __restrict__ P)
{
    __shared__ short Ap[8192];
    __shared__ short Bw[8192];
    const int tid = threadIdx.x;
    const int l = tid & 63, w = tid >> 6;
    const int n0 = blockIdx.x * 128, co0 = blockIdx.y * 128, split = blockIdx.z;
    const int wr = w >> 1, wc = w & 1;
    const int lm = l & 15, lq = l >> 4;
    const int rswz = (lm & 7) << 3;
    const int kt0 = split * KT_PER;

    const int colA = 8 * ((l & 7) ^ ((l >> 3) & 7));
    int rA[4];
    #pragma unroll
    for (int j = 0; j < 4; ++j)
        rA[j] = n0 + w * 32 + j * 8 + (l >> 3);
    const short* bbase = wrb_sw + ((size_t)blockIdx.y * KTILES) * 8192 + (w * 4) * 512 + l * 8;

    f32x4 acc[4][4] = {};

    for (int i = 0; i < KT_PER; ++i) {
        const int kt = kt0 + i;
        const int k = kt >> 2, ci0 = (kt & 3) * 64;
        #pragma unroll
        for (int j = 0; j < 4; ++j)
            gload16(S + ((size_t)k * NN + rA[j]) * 256 + ci0 + colA, &Ap[(w * 4 + j) * 512]);
        const short* b = bbase + (size_t)kt * 8192;
        #pragma unroll
        for (int j = 0; j < 4; ++j)
            gload16(b + j * 512, &Bw[(w * 4 + j) * 512]);
        __syncthreads();
        #pragma unroll
        for (int ks = 0; ks < 2; ++ks) {
            const int c = (ks * 32 + lq * 8) ^ rswz;
            short8 a[4], bf[4];
            #pragma unroll
            for (int m = 0; m < 4; ++m)
                a[m] = *(const short8*)&Ap[(wr * 64 + m * 16 + lm) * 64 + c];
            #pragma unroll
            for (int nb = 0; nb < 4; ++nb)
                bf[nb] = *(const short8*)&Bw[(wc * 64 + nb * 16 + lm) * 64 + c];
            #pragma unroll
            for (int m = 0; m < 4; ++m)
            #pragma unroll
            for (int nb = 0; nb < 4; ++nb)
                acc[m][nb] = MFMA16(a[m], bf[nb], acc[m][nb], 0, 0, 0);
        }
        __syncthreads();
    }
    #pragma unroll
    for (int m = 0; m < 4; ++m)
    #pragma unroll
    for (int nb = 0; nb < 4; ++nb) {
        int co = co0 + wc * 64 + nb * 16 + lm;
        int n = n0 + wr * 64 + m * 16 + lq * 4;
        *(f32x4*)(P + ((size_t)split * 256 + co) * NN + n) = acc[m][nb];
    }
}

// ---------------------------------------------------------------- reduces
template<bool RELU>
__global__ __launch_bounds__(256) void reduce_k(
    const float* __restrict__ P, const float* __restrict__ bias,
    float* __restrict__ dst, int Cout, int CP)
{
    int id = blockIdx.x * 256 + threadIdx.x;
    int total = Cout * (NN / 4);
    if (id >= total) return;
    int co = id / (NN / 4), n4 = id - co * (NN / 4);
    const float* p0 = P + ((size_t)co) * NN + n4 * 4;
    f32x4 v = *(const f32x4*)p0;
    #pragma unroll
    for (int s = 1; s < NSPLIT; ++s) {
        f32x4 u = *(const f32x4*)(p0 + (size_t)s * CP * NN);
        #pragma unroll
        for (int q = 0; q < 4; ++q) v[q] += u[q];
    }
    float bv = bias[co];
    #pragma unroll
    for (int q = 0; q < 4; ++q) {
        float f = v[q] + bv;
        if (RELU) f = fmaxf(f, 0.f);
        v[q] = f;
    }
    *(f32x4*)(dst + (size_t)co * NN + n4 * 4) = v;
}

// bf16 3D-padded transposed output (h layers): bias+relu+cvt+transpose fused
__global__ __launch_bounds__(256) void reduce_bf3(
    const float* __restrict__ P, const float* __restrict__ bias,
    short* __restrict__ dst)
{
    __shared__ float T[64][65];
    const int lane = threadIdx.x & 63, wave = threadIdx.x >> 6;
    const int n0 = blockIdx.x * 64, co0 = blockIdx.y * 64;
    #pragma unroll
    for (int j = 0; j < 16; ++j) {
        int co_l = wave * 16 + j, co = co0 + co_l;
        const float* p0 = P + (size_t)co * NN + n0 + lane;
        float a = p0[0];
        #pragma unroll
        for (int s = 1; s < NSPLIT; ++s) a += p0[(size_t)s * 256 * NN];
        T[co_l][lane] = fmaxf(a + bias[co], 0.f);
    }
    __syncthreads();
    #pragma unroll
    for (int j = 0; j < 16; ++j) {
        int n_l = wave * 16 + j;
        dst[(size_t)n3_of(n0 + n_l) * 256 + co0 + lane] = f2bf(T[lane][n_l]);
    }
}

// ----------------------------------------------------------------
extern "C" void kernel_launch(void* const* d_in, const int* in_sizes, int n_in,
                              void* d_out, int out_size, void* d_ws, size_t ws_size,
                              hipStream_t stream)
{
    const float* x   = (const float*)d_in[0];
    const float* l1w = (const float*)d_in[1];
    const float* l1b = (const float*)d_in[2];
    const float* l2w = (const float*)d_in[3];
    const float* l2b = (const float*)d_in[4];
    const float* l3w = (const float*)d_in[5];
    const float* l3b = (const float*)d_in[6];
    const float* dfw = (const float*)d_in[7];
    const float* dfb = (const float*)d_in[8];
    const float* c3w = (const float*)d_in[9];
    const float* c3b = (const float*)d_in[10];
    float* out = (float*)d_out;

    // ---- workspace ----
    // Overlay region [0, 63.7MB): S (sample phase) over conv-phase-only buffers.
    char* base = (char*)d_ws;
    short* S    = (short*)base;                              // 27*NN*256*2 = 63,700,992
    short* h1b  = (short*)(base);                            // 3,461,120 each
    short* h2b  = (short*)(base + 3461120);
    short* h3b  = (short*)(base + 6922240);
    short* wrb1 = (short*)(base + 10383360);                 // 3,538,944 each
    short* wrb2 = (short*)(base + 13922304);
    short* wrb3 = (short*)(base + 17461248);
    short* wrbd = (short*)(base + 21000192);                 // 1,769,472 (ends 22.77MB < 63.7MB)
    // Non-overlaid region (live across the sample phase):
    char* q = base + 63700992;
    short* xbf3 = (short*)q; q += 3461120;                   // N3*256*2
    float* offs = (float*)q; q += 1492992;                   // 81*NN*4
    short* wrbc = (short*)q; q += 3538944;                   // 256*KDIM*2
    float* P    = (float*)q;                                 // 6*256*NN*4 = 28,311,552

    // zero pads (interiors fully overwritten each call)
    hipMemsetAsync(xbf3, 0, (size_t)N3 * 256 * 2, stream);
    hipMemsetAsync(h1b,  0, (size_t)3 * N3 * 256 * 2, stream);

    transpose_k<<<dim3(72, 4), dim3(256), 0, stream>>>(x, xbf3);
    repack_w_k<<<dim3(256), dim3(256), 0, stream>>>(l1w, wrb1, 256);
    repack_w_k<<<dim3(256), dim3(256), 0, stream>>>(l2w, wrb2, 256);
    repack_w_k<<<dim3(256), dim3(256), 0, stream>>>(l3w, wrb3, 256);
    repack_w_k<<<dim3(256), dim3(256), 0, stream>>>(c3w, wrbc, 256);
    repack_w_k<<<dim3(128), dim3(256), 0, stream>>>(dfw, wrbd, 81);

    const dim3 blk(256);
    const int rg81 = (81 * (NN / 4) + 255) / 256;     // 365
    const int rg256 = (256 * (NN / 4) + 255) / 256;   // 1152

    gemm_conv_sk<256><<<dim3(36, 2, NSPLIT), blk, 0, stream>>>(xbf3, wrb1, P);
    reduce_bf3       <<<dim3(72, 4),         blk, 0, stream>>>(P, l1b, h1b);
    gemm_conv_sk<256><<<dim3(36, 2, NSPLIT), blk, 0, stream>>>(h1b, wrb2, P);
    reduce_bf3       <<<dim3(72, 4),         blk, 0, stream>>>(P, l2b, h2b);
    gemm_conv_sk<256><<<dim3(36, 2, NSPLIT), blk, 0, stream>>>(h2b, wrb3, P);
    reduce_bf3       <<<dim3(72, 4),         blk, 0, stream>>>(P, l3b, h3b);
    gemm_conv_sk<128><<<dim3(36, 1, NSPLIT), blk, 0, stream>>>(h3b, wrbd, P);
    reduce_k<false>  <<<dim3(rg81),          blk, 0, stream>>>(P, dfb, offs, 81, 128);

    sample_k<<<dim3(72, 27), blk, 0, stream>>>(xbf3, offs, S);
    gemm_deform_sk<<<dim3(36, 2, NSPLIT), blk, 0, stream>>>(S, wrbc, P);
    reduce_k<false><<<dim3(rg256), blk, 0, stream>>>(P, c3b, out, 256, 256);
}